// Round 1
// baseline (336.989 us; speedup 1.0000x reference)
//
#include <hip/hip_runtime.h>

typedef unsigned short u16;
typedef __bf16 bf16_t;
typedef bf16_t bf16x8 __attribute__((ext_vector_type(8)));
typedef u16 u16x8 __attribute__((ext_vector_type(8)));
typedef float f32x4 __attribute__((ext_vector_type(4)));

#define DEVI __device__ __forceinline__

// B=2, S=1024, E=1024, H=16, DH=64, MAXLEN=2048, table=4095

DEVI u16 f2bf(float f) {
    unsigned u = __builtin_bit_cast(unsigned, f);
    u = (u + 0x7FFFu + ((u >> 16) & 1u)) >> 16;
    return (u16)u;
}
DEVI float bf2f(u16 b) {
    unsigned u = ((unsigned)b) << 16;
    return __builtin_bit_cast(float, u);
}
DEVI f32x4 mfma16(u16x8 a, u16x8 b, f32x4 c) {
    return __builtin_amdgcn_mfma_f32_16x16x32_bf16(
        __builtin_bit_cast(bf16x8, a), __builtin_bit_cast(bf16x8, b), c, 0, 0, 0);
}

// ---------------- convert fp32 -> bf16 (query,key,value,emb) ----------------
__global__ __launch_bounds__(256) void cvt_kernel(
    const float* __restrict__ q, const float* __restrict__ k, const float* __restrict__ v,
    const float* __restrict__ emb,
    u16* __restrict__ xq, u16* __restrict__ xk, u16* __restrict__ xv, u16* __restrict__ embb)
{
    const long NQ = 2097152;   // 2*1024*1024
    const long NE = 262080;    // 4095*64
    long i4 = ((long)blockIdx.x * 256 + threadIdx.x) * 4;
    if (i4 < 3 * NQ) {
        int which = (int)(i4 >> 21);
        long off = i4 & (NQ - 1);
        const float* src = which == 0 ? q : (which == 1 ? k : v);
        u16* dst = which == 0 ? xq : (which == 1 ? xk : xv);
        float4 f = *(const float4*)(src + off);
        ushort4 o; o.x = f2bf(f.x); o.y = f2bf(f.y); o.z = f2bf(f.z); o.w = f2bf(f.w);
        *(ushort4*)(dst + off) = o;
    } else {
        long off = i4 - 3 * NQ;
        if (off < NE) {
            float4 f = *(const float4*)(emb + off);
            ushort4 o; o.x = f2bf(f.x); o.y = f2bf(f.y); o.z = f2bf(f.z); o.w = f2bf(f.w);
            *(ushort4*)(embb + off) = o;
        }
    }
}

// ---------------- W [K][N] fp32 -> WT [N][K] bf16 (tiled transpose) ---------
__global__ __launch_bounds__(256) void wt_kernel(
    const float* __restrict__ w0, const float* __restrict__ w1,
    const float* __restrict__ w2, const float* __restrict__ w3,
    u16* __restrict__ t0, u16* __restrict__ t1, u16* __restrict__ t2, u16* __restrict__ t3)
{
    int z = blockIdx.z;
    const float* W = z == 0 ? w0 : (z == 1 ? w1 : (z == 2 ? w2 : w3));
    u16* T = z == 0 ? t0 : (z == 1 ? t1 : (z == 2 ? t2 : t3));
    __shared__ float tile[64][65];
    int k0 = blockIdx.y * 64, n0 = blockIdx.x * 64;
    int tx = threadIdx.x, ty = threadIdx.y;   // (64,4)
    for (int r = ty; r < 64; r += 4)
        tile[r][tx] = W[(long)(k0 + r) * 1024 + n0 + tx];
    __syncthreads();
    for (int r = ty; r < 64; r += 4)
        T[(long)(n0 + r) * 1024 + k0 + tx] = f2bf(tile[tx][r]);
}

// ---------------- bf16 MFMA GEMM: C[M=2048][N=1024] = A[M][K=1024] @ WT[N][K]^T
// mode 0: q-proj ((acc+b)*0.125 -> qb [B,H,S,DH] bf16)
// mode 1: k-proj ((acc+b)      -> kb [B,H,S,DH] bf16)
// mode 2: v-proj ((acc+b)      -> vT [B,H,DH,S] bf16)
// mode 3: out-proj ((acc+b)    -> fp32 [M][N])
__global__ __launch_bounds__(256) void gemm_kernel(
    const u16* __restrict__ A0, const u16* __restrict__ A1, const u16* __restrict__ A2,
    const u16* __restrict__ W0, const u16* __restrict__ W1, const u16* __restrict__ W2,
    const float* __restrict__ bias0, const float* __restrict__ bias1, const float* __restrict__ bias2,
    u16* __restrict__ o0, u16* __restrict__ o1, u16* __restrict__ o2,
    float* __restrict__ ofp, int mode_base)
{
    int z = blockIdx.z;
    int mode = mode_base + z;
    const u16* A = z == 0 ? A0 : (z == 1 ? A1 : A2);
    const u16* W = z == 0 ? W0 : (z == 1 ? W1 : W2);
    const float* bias = z == 0 ? bias0 : (z == 1 ? bias1 : bias2);
    u16* ob = z == 0 ? o0 : (z == 1 ? o1 : o2);

    __shared__ u16 la[128][40];   // stride 80B = 5*16B, 2-way bank alias (free)
    __shared__ u16 lw[128][40];

    int m0 = blockIdx.y * 128, n0 = blockIdx.x * 128;
    int t = threadIdx.x;
    int lane = t & 63, wid = t >> 6;
    int l15 = lane & 15, quad = lane >> 4;
    int wm = (wid >> 1) * 64, wn = (wid & 1) * 64;
    int srow = t >> 2, scol = (t & 3) * 8;

    f32x4 acc[4][4] = {};

    for (int k0 = 0; k0 < 1024; k0 += 32) {
        __syncthreads();
        *(u16x8*)&la[srow][scol]      = *(const u16x8*)&A[(long)(m0 + srow) * 1024 + k0 + scol];
        *(u16x8*)&la[srow + 64][scol] = *(const u16x8*)&A[(long)(m0 + srow + 64) * 1024 + k0 + scol];
        *(u16x8*)&lw[srow][scol]      = *(const u16x8*)&W[(long)(n0 + srow) * 1024 + k0 + scol];
        *(u16x8*)&lw[srow + 64][scol] = *(const u16x8*)&W[(long)(n0 + srow + 64) * 1024 + k0 + scol];
        __syncthreads();
        u16x8 af[4], bfr[4];
#pragma unroll
        for (int mt = 0; mt < 4; mt++) af[mt]  = *(const u16x8*)&la[wm + mt * 16 + l15][quad * 8];
#pragma unroll
        for (int nt = 0; nt < 4; nt++) bfr[nt] = *(const u16x8*)&lw[wn + nt * 16 + l15][quad * 8];
#pragma unroll
        for (int mt = 0; mt < 4; mt++)
#pragma unroll
            for (int nt = 0; nt < 4; nt++)
                acc[mt][nt] = mfma16(af[mt], bfr[nt], acc[mt][nt]);
    }

#pragma unroll
    for (int mt = 0; mt < 4; mt++)
#pragma unroll
        for (int nt = 0; nt < 4; nt++)
#pragma unroll
            for (int reg = 0; reg < 4; reg++) {
                int gm = m0 + wm + mt * 16 + quad * 4 + reg;   // C row = quad*4+reg
                int gn = n0 + wn + nt * 16 + l15;              // C col = lane&15
                float val = acc[mt][nt][reg] + bias[gn];
                if (mode == 0) {
                    val *= 0.125f;   // 1/sqrt(DH)
                    long o = ((long)((gm >> 10) * 16 + (gn >> 6)) << 16) + ((gm & 1023) << 6) + (gn & 63);
                    ob[o] = f2bf(val);
                } else if (mode == 1) {
                    long o = ((long)((gm >> 10) * 16 + (gn >> 6)) << 16) + ((gm & 1023) << 6) + (gn & 63);
                    ob[o] = f2bf(val);
                } else if (mode == 2) {
                    long o = ((long)((gm >> 10) * 16 + (gn >> 6)) << 16) + ((long)(gn & 63) << 10) + (gm & 1023);
                    ob[o] = f2bf(val);
                } else {
                    ofp[(long)gm * 1024 + gn] = val;
                }
            }
}

// ---------------- Gc[u][c] = q[u] . emb[1024 + (u&1023) + c], c in [0,1024) --
// Skewed GEMM: per 16-row block, C[r][w] = q[u0+r] . emb[1024+i0+w], Gc[u0+r][w-r]=C[r][w]
__global__ __launch_bounds__(256) void gc_kernel(
    const u16* __restrict__ qb, const u16* __restrict__ embb, u16* __restrict__ Gc)
{
    int u0 = blockIdx.x * 16;
    int i0 = u0 & 1023;
    int t = threadIdx.x, lane = t & 63, wid = t >> 6;
    int l15 = lane & 15, quad = lane >> 4;

    u16x8 aq[2];
    long qoff = (long)(u0 + l15) * 64 + quad * 8;
    aq[0] = *(const u16x8*)&qb[qoff];
    aq[1] = *(const u16x8*)&qb[qoff + 32];

    for (int tt = wid; tt < 65; tt += 4) {
        int w0 = tt * 16;
        long ebase = (long)(1024 + i0 + w0 + l15) * 64 + quad * 8;
        u16x8 b0 = *(const u16x8*)&embb[ebase];
        u16x8 b1 = *(const u16x8*)&embb[ebase + 32];
        f32x4 c = {};
        c = mfma16(aq[0], b0, c);
        c = mfma16(aq[1], b1, c);
#pragma unroll
        for (int reg = 0; reg < 4; reg++) {
            int r = quad * 4 + reg;
            int cc = w0 + l15 - r;
            if (cc >= 0 && cc < 1024)
                Gc[(long)(u0 + r) * 1024 + cc] = f2bf(c[reg]);
        }
    }
}

// ---------------- flash attention with fused rel gather ---------------------
__global__ __launch_bounds__(256) void flash_kernel(
    const u16* __restrict__ qb, const u16* __restrict__ kb, const u16* __restrict__ vT,
    const u16* __restrict__ Gc, const float* __restrict__ rpb, u16* __restrict__ attn)
{
    int bh = blockIdx.z * 16 + blockIdx.y;
    int i_base = blockIdx.x * 64;
    int t = threadIdx.x, lane = t & 63, wid = t >> 6;
    int l15 = lane & 15, quad = lane >> 4;
    int i0w = i_base + wid * 16;

    __shared__ u16 lds_k[64][72];      // [j][d], stride 144B = 9*16B
    __shared__ u16 lds_v[64][72];      // [d][j]
    __shared__ u16 lds_p[4][16][72];   // per-wave P

    u16x8 aq[2];
    {
        long qoff = ((long)bh * 1024 + i0w + l15) * 64 + quad * 8;
        aq[0] = *(const u16x8*)&qb[qoff];
        aq[1] = *(const u16x8*)&qb[qoff + 32];
    }
    float m_r[4], l_r[4];
    f32x4 o_acc[4] = {};
#pragma unroll
    for (int r = 0; r < 4; r++) { m_r[r] = -1e30f; l_r[r] = 0.f; }

    int srow = t >> 2, scol = (t & 3) * 8;
    const u16* kbase = kb + (long)bh * 65536;
    const u16* vbase = vT + (long)bh * 65536;
    const u16* gbase = Gc + (long)bh * 1048576;

    for (int jt = 0; jt < 16; jt++) {
        int j0 = jt * 64;
        __syncthreads();
        *(u16x8*)&lds_k[srow][scol]      = *(const u16x8*)&kbase[(long)(j0 + srow) * 64 + scol];
        *(u16x8*)&lds_k[srow][scol + 32] = *(const u16x8*)&kbase[(long)(j0 + srow) * 64 + scol + 32];
        *(u16x8*)&lds_v[srow][scol]      = *(const u16x8*)&vbase[(long)srow * 1024 + j0 + scol];
        *(u16x8*)&lds_v[srow][scol + 32] = *(const u16x8*)&vbase[(long)srow * 1024 + j0 + scol + 32];
        __syncthreads();

        // S = q @ k^T  (16 rows x 64 cols per wave)
        f32x4 s_acc[4];
#pragma unroll
        for (int nt = 0; nt < 4; nt++) {
            u16x8 b0 = *(const u16x8*)&lds_k[nt * 16 + l15][quad * 8];
            u16x8 b1 = *(const u16x8*)&lds_k[nt * 16 + l15][quad * 8 + 32];
            f32x4 c = {};
            c = mfma16(aq[0], b0, c);
            c = mfma16(aq[1], b1, c);
            s_acc[nt] = c;
        }

        // + rel (Gc gather) + rpb
#pragma unroll
        for (int nt = 0; nt < 4; nt++) {
            int jj = j0 + nt * 16 + l15;
#pragma unroll
            for (int reg = 0; reg < 4; reg++) {
                int ii = i0w + quad * 4 + reg;
                float extra;
                if (jj <= ii)            extra = bf2f(gbase[(long)ii * 1024 + (ii - jj)]);
                else if (jj == ii + 1)   extra = 0.f;
                else                     extra = bf2f(gbase[(long)(ii + 1) * 1024 + (ii - jj + 1025)]);
                extra += rpb[ii - jj + 2047];
                s_acc[nt][reg] += extra;
            }
        }

        // online softmax (rows live at quad*4+reg across the quad's 16 lanes)
#pragma unroll
        for (int reg = 0; reg < 4; reg++) {
            float mx = fmaxf(fmaxf(s_acc[0][reg], s_acc[1][reg]), fmaxf(s_acc[2][reg], s_acc[3][reg]));
            for (int off = 1; off < 16; off <<= 1) mx = fmaxf(mx, __shfl_xor(mx, off, 64));
            float mnew = fmaxf(m_r[reg], mx);
            float alpha = __expf(m_r[reg] - mnew);
            float rs = 0.f;
#pragma unroll
            for (int nt = 0; nt < 4; nt++) {
                float p = __expf(s_acc[nt][reg] - mnew);
                s_acc[nt][reg] = p;
                rs += p;
            }
            for (int off = 1; off < 16; off <<= 1) rs += __shfl_xor(rs, off, 64);
            l_r[reg] = l_r[reg] * alpha + rs;
            m_r[reg] = mnew;
#pragma unroll
            for (int dt = 0; dt < 4; dt++) o_acc[dt][reg] *= alpha;
        }

        // P: C-layout -> LDS -> A-layout
#pragma unroll
        for (int nt = 0; nt < 4; nt++)
#pragma unroll
            for (int reg = 0; reg < 4; reg++)
                lds_p[wid][quad * 4 + reg][nt * 16 + l15] = f2bf(s_acc[nt][reg]);

        u16x8 pf0 = *(const u16x8*)&lds_p[wid][l15][quad * 8];
        u16x8 pf1 = *(const u16x8*)&lds_p[wid][l15][quad * 8 + 32];
#pragma unroll
        for (int dt = 0; dt < 4; dt++) {
            u16x8 v0 = *(const u16x8*)&lds_v[dt * 16 + l15][quad * 8];
            u16x8 v1 = *(const u16x8*)&lds_v[dt * 16 + l15][quad * 8 + 32];
            o_acc[dt] = mfma16(pf0, v0, o_acc[dt]);
            o_acc[dt] = mfma16(pf1, v1, o_acc[dt]);
        }
    }

    int b = bh >> 4, h = bh & 15;
#pragma unroll
    for (int dt = 0; dt < 4; dt++)
#pragma unroll
        for (int reg = 0; reg < 4; reg++) {
            int ii = i0w + quad * 4 + reg;
            float val = o_acc[dt][reg] / l_r[reg];
            attn[((long)(b * 1024 + ii)) * 1024 + h * 64 + dt * 16 + l15] = f2bf(val);
        }
}

// ---------------------------------------------------------------------------
extern "C" void kernel_launch(void* const* d_in, const int* in_sizes, int n_in,
                              void* d_out, int out_size, void* d_ws, size_t ws_size,
                              hipStream_t stream)
{
    const float* query = (const float*)d_in[0];
    const float* key_  = (const float*)d_in[1];
    const float* value = (const float*)d_in[2];
    const float* Wq = (const float*)d_in[3];
    const float* bq = (const float*)d_in[4];
    const float* Wk = (const float*)d_in[5];
    const float* bk = (const float*)d_in[6];
    const float* Wv = (const float*)d_in[7];
    const float* bv = (const float*)d_in[8];
    const float* Wo = (const float*)d_in[9];
    const float* bo = (const float*)d_in[10];
    const float* emb = (const float*)d_in[11];
    const float* rpb = (const float*)d_in[12];

    char* ws = (char*)d_ws;
    u16* xq   = (u16*)(ws + 0);
    u16* xk   = (u16*)(ws + 4194304);
    u16* xv   = (u16*)(ws + 8388608);
    u16* WqT  = (u16*)(ws + 12582912);
    u16* WkT  = (u16*)(ws + 14680064);
    u16* WvT  = (u16*)(ws + 16777216);
    u16* WoT  = (u16*)(ws + 18874368);
    u16* embb = (u16*)(ws + 20971520);
    u16* qb   = (u16*)(ws + 21495808);
    u16* kb   = (u16*)(ws + 25690112);
    u16* vT   = (u16*)(ws + 29884416);
    u16* attn = (u16*)(ws + 34078720);
    u16* Gc   = (u16*)(ws + 38273024);   // 64 MB; total ws use ~100.5 MB

    cvt_kernel<<<6400, 256, 0, stream>>>(query, key_, value, emb, xq, xk, xv, embb);
    wt_kernel<<<dim3(16, 16, 4), dim3(64, 4), 0, stream>>>(Wq, Wk, Wv, Wo, WqT, WkT, WvT, WoT);
    gemm_kernel<<<dim3(8, 16, 3), 256, 0, stream>>>(xq, xk, xv, WqT, WkT, WvT,
                                                    bq, bk, bv, qb, kb, vT, nullptr, 0);
    gc_kernel<<<2048, 256, 0, stream>>>(qb, embb, Gc);
    flash_kernel<<<dim3(16, 16, 2), 256, 0, stream>>>(qb, kb, vT, Gc, rpb, attn);
    gemm_kernel<<<dim3(8, 16, 1), 256, 0, stream>>>(attn, nullptr, nullptr, WoT, nullptr, nullptr,
                                                    bo, nullptr, nullptr,
                                                    nullptr, nullptr, nullptr, (float*)d_out, 3);
}

// Round 2
// 250.708 us; speedup vs baseline: 1.3442x; 1.3442x over previous
//
#include <hip/hip_runtime.h>

typedef unsigned short u16;
typedef __bf16 bf16_t;
typedef bf16_t bf16x8 __attribute__((ext_vector_type(8)));
typedef u16 u16x8 __attribute__((ext_vector_type(8)));
typedef float f32x4 __attribute__((ext_vector_type(4)));

#define DEVI __device__ __forceinline__

// B=2, S=1024, E=1024, H=16, DH=64, MAXLEN=2048, table=4095

DEVI u16 f2bf(float f) {
    unsigned u = __builtin_bit_cast(unsigned, f);
    u = (u + 0x7FFFu + ((u >> 16) & 1u)) >> 16;
    return (u16)u;
}
DEVI float bf2f(u16 b) {
    unsigned u = ((unsigned)b) << 16;
    return __builtin_bit_cast(float, u);
}
DEVI f32x4 mfma16(u16x8 a, u16x8 b, f32x4 c) {
    return __builtin_amdgcn_mfma_f32_16x16x32_bf16(
        __builtin_bit_cast(bf16x8, a), __builtin_bit_cast(bf16x8, b), c, 0, 0, 0);
}
// async global->LDS, 16B per lane; LDS dest = base + lane*16 (wave-uniform base)
DEVI void gl2lds(const u16* g, u16* l) {
    __builtin_amdgcn_global_load_lds(
        (__attribute__((address_space(1))) void*)g,
        (__attribute__((address_space(3))) void*)l, 16, 0, 0);
}

// ---------------- convert fp32 -> bf16 (query,key,value,emb) + Brel2 diag fill
__global__ __launch_bounds__(256) void cvt_kernel(
    const float* __restrict__ q, const float* __restrict__ k, const float* __restrict__ v,
    const float* __restrict__ emb, const float* __restrict__ rpb,
    u16* __restrict__ xq, u16* __restrict__ xk, u16* __restrict__ xv, u16* __restrict__ embb,
    u16* __restrict__ Brel2)
{
    const long NQ = 2097152;   // 2*1024*1024
    const long NE = 262080;    // 4095*64
    if (blockIdx.x >= 6400) {
        // diag fill: Brel2[u][i+1] = rpb[2046] (the j=i+1 slot: rel==0 after shift)
        int u = (blockIdx.x - 6400) * 256 + threadIdx.x;   // 0..32767
        int i = u & 1023;
        if (i <= 1022)
            Brel2[((long)u << 10) + i + 1] = f2bf(rpb[2046]);
        return;
    }
    long i4 = ((long)blockIdx.x * 256 + threadIdx.x) * 4;
    if (i4 < 3 * NQ) {
        int which = (int)(i4 >> 21);
        long off = i4 & (NQ - 1);
        const float* src = which == 0 ? q : (which == 1 ? k : v);
        u16* dst = which == 0 ? xq : (which == 1 ? xk : xv);
        float4 f = *(const float4*)(src + off);
        ushort4 o; o.x = f2bf(f.x); o.y = f2bf(f.y); o.z = f2bf(f.z); o.w = f2bf(f.w);
        *(ushort4*)(dst + off) = o;
    } else {
        long off = i4 - 3 * NQ;
        if (off < NE) {
            float4 f = *(const float4*)(emb + off);
            ushort4 o; o.x = f2bf(f.x); o.y = f2bf(f.y); o.z = f2bf(f.z); o.w = f2bf(f.w);
            *(ushort4*)(embb + off) = o;
        }
    }
}

// ---------------- W [K][N] fp32 -> WT [N][K] bf16 (tiled transpose) ---------
__global__ __launch_bounds__(256) void wt_kernel(
    const float* __restrict__ w0, const float* __restrict__ w1,
    const float* __restrict__ w2, const float* __restrict__ w3,
    u16* __restrict__ t0, u16* __restrict__ t1, u16* __restrict__ t2, u16* __restrict__ t3)
{
    int z = blockIdx.z;
    const float* W = z == 0 ? w0 : (z == 1 ? w1 : (z == 2 ? w2 : w3));
    u16* T = z == 0 ? t0 : (z == 1 ? t1 : (z == 2 ? t2 : t3));
    __shared__ float tile[64][65];
    int k0 = blockIdx.y * 64, n0 = blockIdx.x * 64;
    int tx = threadIdx.x, ty = threadIdx.y;   // (64,4)
    for (int r = ty; r < 64; r += 4)
        tile[r][tx] = W[(long)(k0 + r) * 1024 + n0 + tx];
    __syncthreads();
    for (int r = ty; r < 64; r += 4)
        T[(long)(n0 + r) * 1024 + k0 + tx] = f2bf(tile[tx][r]);
}

// ---------------- bf16 MFMA GEMM, global_load_lds staging -------------------
// C[M][N=1024] tile (MT*32) x 128; A[M][1024], WT[N][1024] (both row-major K)
// LDS layout: [row][32 u16], k-chunks of 8 u16 stored at pos p = c ^ ((row>>1)&3)
// mode 0: q-proj ((acc+b)*0.125 -> qb [B,H,S,DH]); 1: k-proj -> kb; 2: v-proj -> vT [B,H,DH,S];
// mode 3: out-proj -> fp32 [M][N]
template<int MT>
__global__ __launch_bounds__(256) void gemm_kernel(
    const u16* __restrict__ A0, const u16* __restrict__ A1, const u16* __restrict__ A2,
    const u16* __restrict__ W0, const u16* __restrict__ W1, const u16* __restrict__ W2,
    const float* __restrict__ bias0, const float* __restrict__ bias1, const float* __restrict__ bias2,
    u16* __restrict__ o0, u16* __restrict__ o1, u16* __restrict__ o2,
    float* __restrict__ ofp, int mode_base)
{
    int z = blockIdx.z;
    int mode = mode_base + z;
    const u16* A = z == 0 ? A0 : (z == 1 ? A1 : A2);
    const u16* W = z == 0 ? W0 : (z == 1 ? W1 : W2);
    const float* bias = z == 0 ? bias0 : (z == 1 ? bias1 : bias2);
    u16* ob = z == 0 ? o0 : (z == 1 ? o1 : o2);

    constexpr int MROWS = MT * 32;
    __shared__ u16 la[MROWS * 32];
    __shared__ u16 lw[128 * 32];

    int m0 = blockIdx.y * MROWS, n0 = blockIdx.x * 128;
    int t = threadIdx.x, lane = t & 63, wid = t >> 6;
    int l15 = lane & 15, quad = lane >> 4;
    int wm = (wid >> 1) * (MT * 16), wn = (wid & 1) * 64;
    int sr = lane >> 2, sp = lane & 3;   // staging: 16 rows x 4 chunks per instr

    f32x4 acc[MT][4] = {};

    for (int k0 = 0; k0 < 1024; k0 += 32) {
        __syncthreads();
#pragma unroll
        for (int q = 0; q < MT / 2; q++) {
            int r = wid * (MT * 8) + q * 16 + sr;
            int c = sp ^ ((r >> 1) & 3);
            gl2lds(A + (long)(m0 + r) * 1024 + k0 + c * 8, la + (wid * (MT * 8) + q * 16) * 32);
        }
#pragma unroll
        for (int q = 0; q < 2; q++) {
            int r = wid * 32 + q * 16 + sr;
            int c = sp ^ ((r >> 1) & 3);
            gl2lds(W + (long)(n0 + r) * 1024 + k0 + c * 8, lw + (wid * 32 + q * 16) * 32);
        }
        __syncthreads();
        u16x8 af[MT], bfr[4];
#pragma unroll
        for (int mt = 0; mt < MT; mt++) {
            int r = wm + mt * 16 + l15;
            af[mt] = *(const u16x8*)&la[r * 32 + ((quad ^ ((r >> 1) & 3)) * 8)];
        }
#pragma unroll
        for (int nt = 0; nt < 4; nt++) {
            int r = wn + nt * 16 + l15;
            bfr[nt] = *(const u16x8*)&lw[r * 32 + ((quad ^ ((r >> 1) & 3)) * 8)];
        }
#pragma unroll
        for (int mt = 0; mt < MT; mt++)
#pragma unroll
            for (int nt = 0; nt < 4; nt++)
                acc[mt][nt] = mfma16(af[mt], bfr[nt], acc[mt][nt]);
    }

#pragma unroll
    for (int mt = 0; mt < MT; mt++)
#pragma unroll
        for (int nt = 0; nt < 4; nt++)
#pragma unroll
            for (int reg = 0; reg < 4; reg++) {
                int gm = m0 + wm + mt * 16 + quad * 4 + reg;   // C row = quad*4+reg
                int gn = n0 + wn + nt * 16 + l15;              // C col = lane&15
                float val = acc[mt][nt][reg] + bias[gn];
                if (mode == 0) {
                    val *= 0.125f;   // 1/sqrt(DH)
                    long o = ((long)((gm >> 10) * 16 + (gn >> 6)) << 16) + ((gm & 1023) << 6) + (gn & 63);
                    ob[o] = f2bf(val);
                } else if (mode == 1) {
                    long o = ((long)((gm >> 10) * 16 + (gn >> 6)) << 16) + ((gm & 1023) << 6) + (gn & 63);
                    ob[o] = f2bf(val);
                } else if (mode == 2) {
                    long o = ((long)((gm >> 10) * 16 + (gn >> 6)) << 16) + ((long)(gn & 63) << 10) + (gm & 1023);
                    ob[o] = f2bf(val);
                } else {
                    ofp[(long)gm * 1024 + gn] = val;
                }
            }
}

// ---------------- Gc skewed GEMM, writing Brel2[bh][i][j] = rel+rpb directly -
// C[r][w] = q[u0+r] . emb[1024+i0+w]; element (u=u0+r, cc=w-r):
//   cc <= i          -> Brel2[u][i-cc]        (+rpb[cc+2047])
//   cc >  i (i>=1)   -> Brel2[u-1][i+1024-cc] (+rpb[cc+1022])
__global__ __launch_bounds__(256) void gc_kernel(
    const u16* __restrict__ qb, const u16* __restrict__ embb,
    const float* __restrict__ rpb, u16* __restrict__ Brel2)
{
    int u0 = blockIdx.x * 16;
    int i0 = u0 & 1023;
    int t = threadIdx.x, lane = t & 63, wid = t >> 6;
    int l15 = lane & 15, quad = lane >> 4;

    u16x8 aq[2];
    long qoff = (long)(u0 + l15) * 64 + quad * 8;
    aq[0] = *(const u16x8*)&qb[qoff];
    aq[1] = *(const u16x8*)&qb[qoff + 32];

    for (int tt = wid; tt < 65; tt += 4) {
        int w0 = tt * 16;
        long ebase = (long)(1024 + i0 + w0 + l15) * 64 + quad * 8;
        u16x8 b0 = *(const u16x8*)&embb[ebase];
        u16x8 b1 = *(const u16x8*)&embb[ebase + 32];
        f32x4 c = {};
        c = mfma16(aq[0], b0, c);
        c = mfma16(aq[1], b1, c);
#pragma unroll
        for (int reg = 0; reg < 4; reg++) {
            int r = quad * 4 + reg;
            int cc = w0 + l15 - r;
            if (cc < 0 || cc > 1023) continue;
            int u = u0 + r;
            int i = u & 1023;
            if (cc <= i) {
                Brel2[((long)u << 10) + (i - cc)] = f2bf(c[reg] + rpb[cc + 2047]);
            } else if (i >= 1) {
                Brel2[((long)(u - 1) << 10) + (i + 1024 - cc)] = f2bf(c[reg] + rpb[cc + 1022]);
            }
        }
    }
}

// ---------------- flash attention (j-split x2, partial O/m/l) ---------------
// LDS tiles [64 rows][64 u16], chunk (8 u16) swizzle: pos p = c ^ (row&7)
__global__ __launch_bounds__(256, 4) void flash_kernel(
    const u16* __restrict__ qb, const u16* __restrict__ kb, const u16* __restrict__ vT,
    const u16* __restrict__ Brel2,
    float* __restrict__ Po, float* __restrict__ Pm, float* __restrict__ Pl)
{
    int itile = blockIdx.x;        // 0..15
    int bh = blockIdx.y;           // 0..31
    int js = blockIdx.z;           // 0..1
    int t = threadIdx.x, lane = t & 63, wid = t >> 6;
    int l15 = lane & 15, quad = lane >> 4;
    int i0w = itile * 64 + wid * 16;

    __shared__ u16 lds_k[64 * 64];     // [j][d]
    __shared__ u16 lds_v[64 * 64];     // [d][j]
    __shared__ u16 lds_p[4][16][72];   // per-wave P

    int sr8 = lane >> 3, sp8 = lane & 7;   // staging: 8 rows x 8 chunks per instr

    u16x8 aq[2];
    {
        long qoff = ((long)(bh * 1024) + i0w + l15) * 64 + quad * 8;
        aq[0] = *(const u16x8*)&qb[qoff];
        aq[1] = *(const u16x8*)&qb[qoff + 32];
    }
    float m_r[4], l_r[4];
    f32x4 o_acc[4] = {};
#pragma unroll
    for (int r = 0; r < 4; r++) { m_r[r] = -1e30f; l_r[r] = 0.f; }

    const u16* kbase = kb + (long)bh * 65536;
    const u16* vbase = vT + (long)bh * 65536;
    const u16* bbase = Brel2 + ((long)bh << 20);

    for (int jt = 0; jt < 8; jt++) {
        int j0 = js * 512 + jt * 64;
        __syncthreads();
#pragma unroll
        for (int q = 0; q < 2; q++) {
            int r = wid * 16 + q * 8 + sr8;
            int c = sp8 ^ (r & 7);
            gl2lds(kbase + (long)(j0 + r) * 64 + c * 8, lds_k + (wid * 16 + q * 8) * 64);
            gl2lds(vbase + (long)r * 1024 + j0 + c * 8, lds_v + (wid * 16 + q * 8) * 64);
        }
        __syncthreads();

        // S = q @ k^T  (16 rows x 64 cols per wave)
        f32x4 s_acc[4];
#pragma unroll
        for (int nt = 0; nt < 4; nt++) {
            int r = nt * 16 + l15;
            u16x8 b0 = *(const u16x8*)&lds_k[r * 64 + ((quad ^ (r & 7)) * 8)];
            u16x8 b1 = *(const u16x8*)&lds_k[r * 64 + (((quad + 4) ^ (r & 7)) * 8)];
            f32x4 c = {};
            c = mfma16(aq[0], b0, c);
            c = mfma16(aq[1], b1, c);
            s_acc[nt] = c;
        }

        // + rel+rpb (materialized, coalesced)
#pragma unroll
        for (int nt = 0; nt < 4; nt++) {
            int jj = j0 + nt * 16 + l15;
#pragma unroll
            for (int reg = 0; reg < 4; reg++) {
                int ii = i0w + quad * 4 + reg;
                s_acc[nt][reg] += bf2f(bbase[((long)ii << 10) + jj]);
            }
        }

        // online softmax (rows at quad*4+reg, 16 lanes per row-group)
#pragma unroll
        for (int reg = 0; reg < 4; reg++) {
            float mx = fmaxf(fmaxf(s_acc[0][reg], s_acc[1][reg]), fmaxf(s_acc[2][reg], s_acc[3][reg]));
            for (int off = 1; off < 16; off <<= 1) mx = fmaxf(mx, __shfl_xor(mx, off, 64));
            float mnew = fmaxf(m_r[reg], mx);
            float alpha = __expf(m_r[reg] - mnew);
            float rs = 0.f;
#pragma unroll
            for (int nt = 0; nt < 4; nt++) {
                float p = __expf(s_acc[nt][reg] - mnew);
                s_acc[nt][reg] = p;
                rs += p;
            }
            for (int off = 1; off < 16; off <<= 1) rs += __shfl_xor(rs, off, 64);
            l_r[reg] = l_r[reg] * alpha + rs;
            m_r[reg] = mnew;
#pragma unroll
            for (int dt = 0; dt < 4; dt++) o_acc[dt][reg] *= alpha;
        }

        // P: C-layout -> LDS -> A-layout
#pragma unroll
        for (int nt = 0; nt < 4; nt++)
#pragma unroll
            for (int reg = 0; reg < 4; reg++)
                lds_p[wid][quad * 4 + reg][nt * 16 + l15] = f2bf(s_acc[nt][reg]);

        u16x8 pf0 = *(const u16x8*)&lds_p[wid][l15][quad * 8];
        u16x8 pf1 = *(const u16x8*)&lds_p[wid][l15][quad * 8 + 32];
#pragma unroll
        for (int dt = 0; dt < 4; dt++) {
            int r = dt * 16 + l15;
            u16x8 v0 = *(const u16x8*)&lds_v[r * 64 + ((quad ^ (r & 7)) * 8)];
            u16x8 v1 = *(const u16x8*)&lds_v[r * 64 + (((quad + 4) ^ (r & 7)) * 8)];
            o_acc[dt] = mfma16(pf0, v0, o_acc[dt]);
            o_acc[dt] = mfma16(pf1, v1, o_acc[dt]);
        }
    }

    int blk = (js * 32 + bh) * 16 + itile;
    float* PoB = Po + (long)blk * 4096;
#pragma unroll
    for (int dt = 0; dt < 4; dt++)
#pragma unroll
        for (int reg = 0; reg < 4; reg++) {
            int rr = wid * 16 + quad * 4 + reg;
            PoB[rr * 64 + dt * 16 + l15] = o_acc[dt][reg];
        }
    if (l15 == 0) {
#pragma unroll
        for (int reg = 0; reg < 4; reg++) {
            int rr = wid * 16 + quad * 4 + reg;
            Pm[blk * 64 + rr] = m_r[reg];
            Pl[blk * 64 + rr] = l_r[reg];
        }
    }
}

// ---------------- combine the 2 j-partials -> attn (bf16 [B,S,E]) -----------
__global__ __launch_bounds__(256) void combine_kernel(
    const float* __restrict__ Po, const float* __restrict__ Pm, const float* __restrict__ Pl,
    u16* __restrict__ attn)
{
    int itile = blockIdx.x, bh = blockIdx.y;
    int t = threadIdx.x;
    int c = t & 63, rg = t >> 6;
    int blk0 = bh * 16 + itile;
    int blk1 = (32 + bh) * 16 + itile;
    int b = bh >> 4, h = bh & 15;
    for (int rr = rg; rr < 64; rr += 4) {
        float m0 = Pm[blk0 * 64 + rr], m1 = Pm[blk1 * 64 + rr];
        float ms = fmaxf(m0, m1);
        float e0 = __expf(m0 - ms), e1 = __expf(m1 - ms);
        float l = Pl[blk0 * 64 + rr] * e0 + Pl[blk1 * 64 + rr] * e1;
        float o = Po[(long)blk0 * 4096 + rr * 64 + c] * e0
                + Po[(long)blk1 * 4096 + rr * 64 + c] * e1;
        int ii = itile * 64 + rr;
        attn[((long)(b * 1024 + ii)) * 1024 + h * 64 + c] = f2bf(o / l);
    }
}

// ---------------------------------------------------------------------------
extern "C" void kernel_launch(void* const* d_in, const int* in_sizes, int n_in,
                              void* d_out, int out_size, void* d_ws, size_t ws_size,
                              hipStream_t stream)
{
    const float* query = (const float*)d_in[0];
    const float* key_  = (const float*)d_in[1];
    const float* value = (const float*)d_in[2];
    const float* Wq = (const float*)d_in[3];
    const float* bq = (const float*)d_in[4];
    const float* Wk = (const float*)d_in[5];
    const float* bk = (const float*)d_in[6];
    const float* Wv = (const float*)d_in[7];
    const float* bv = (const float*)d_in[8];
    const float* Wo = (const float*)d_in[9];
    const float* bo = (const float*)d_in[10];
    const float* emb = (const float*)d_in[11];
    const float* rpb = (const float*)d_in[12];

    char* ws = (char*)d_ws;
    // live whole pipeline / early phase:
    u16* xq   = (u16*)(ws + 0);          // 4 MB   (dead after QKV gemm)
    u16* xk   = (u16*)(ws + 4194304);    // 4 MB   (dead after QKV gemm)
    u16* xv   = (u16*)(ws + 8388608);    // 4 MB   (dead after QKV gemm)
    u16* WqT  = (u16*)(ws + 12582912);   // 2 MB   (dead after QKV gemm)
    u16* WkT  = (u16*)(ws + 14680064);   // 2 MB   (dead after QKV gemm)
    u16* WvT  = (u16*)(ws + 16777216);   // 2 MB   (dead after QKV gemm)
    u16* embb = (u16*)(ws + 18874368);   // 512 KB (dead after gc)
    u16* WoT  = (u16*)(ws + 19922944);   // 2 MB   (live till final gemm)
    u16* qb   = (u16*)(ws + 22020096);   // 4 MB   (dead after flash)
    u16* kb   = (u16*)(ws + 26214400);   // 4 MB
    u16* vT   = (u16*)(ws + 30408704);   // 4 MB
    u16* Brel2= (u16*)(ws + 34603008);   // 64 MB -> ends 101711872
    // overlays (regions dead by the time these are written):
    float* Po = (float*)(ws + 0);          // 16 MB over xq/xk/xv/WqT/WkT
    float* Pm = (float*)(ws + 16777216);   // 256 KB over WvT
    float* Pl = (float*)(ws + 17039360);   // 256 KB over WvT
    u16* attn = (u16*)(ws + 22020096);     // 4 MB over qb

    cvt_kernel<<<6528, 256, 0, stream>>>(query, key_, value, emb, rpb, xq, xk, xv, embb, Brel2);
    wt_kernel<<<dim3(16, 16, 4), dim3(64, 4), 0, stream>>>(Wq, Wk, Wv, Wo, WqT, WkT, WvT, WoT);
    gemm_kernel<4><<<dim3(8, 16, 3), 256, 0, stream>>>(xq, xk, xv, WqT, WkT, WvT,
                                                       bq, bk, bv, qb, kb, vT, nullptr, 0);
    gc_kernel<<<2048, 256, 0, stream>>>(qb, embb, rpb, Brel2);
    flash_kernel<<<dim3(16, 32, 2), 256, 0, stream>>>(qb, kb, vT, Brel2, Po, Pm, Pl);
    combine_kernel<<<dim3(16, 32), 256, 0, stream>>>(Po, Pm, Pl, attn);
    gemm_kernel<2><<<dim3(8, 32, 1), 256, 0, stream>>>(attn, nullptr, nullptr, WoT, nullptr, nullptr,
                                                       bo, nullptr, nullptr,
                                                       nullptr, nullptr, nullptr, (float*)d_out, 3);
}